// Round 15
// baseline (232.621 us; speedup 1.0000x reference)
//
#include <hip/hip_runtime.h>
#include <math.h>

// Problem dims (fixed)
#define B_   128
#define L_   256
#define H_   128
#define H2_  256
#define VS_  256

__device__ __forceinline__ float fma4(float4 a, float4 b, float acc) {
    acc = fmaf(a.x, b.x, acc);
    acc = fmaf(a.y, b.y, acc);
    acc = fmaf(a.z, b.z, acc);
    acc = fmaf(a.w, b.w, acc);
    return acc;
}

template <int CTRL>
__device__ __forceinline__ float dpp_add(float x) {
    int y = __builtin_amdgcn_update_dpp(0, __float_as_int(x), CTRL, 0xf, 0xf, true);
    return x + __int_as_float(y);
}
// Full 64-lane sum; total lands in lane 63.
__device__ __forceinline__ float wave_sum(float x) {
    x = dpp_add<0x111>(x);  // row_shr:1
    x = dpp_add<0x112>(x);  // row_shr:2
    x = dpp_add<0x114>(x);  // row_shr:4
    x = dpp_add<0x118>(x);  // row_shr:8
    x = dpp_add<0x142>(x);  // row_bcast:15
    x = dpp_add<0x143>(x);  // row_bcast:31
    return x;
}

// ---------------------------------------------------------------------------
// Kernel 1: per-VOCAB fused FFN (R11) + per-vocab scan tables:
//   F[v] = Wk( LN(embed[v]+FFN(embed[v])) );  n2g[v]=||F[v]||^2;
//   rnag[v]=1/max(||F[v]||,eps); thrg[v]=0.16*n2g[v].
// ---------------------------------------------------------------------------
__global__ __launch_bounds__(256) void k_vffn(
    const float* __restrict__ embed,
    const float* __restrict__ W1, const float* __restrict__ b1,
    const float* __restrict__ W2, const float* __restrict__ b2,
    const float* __restrict__ gamma, const float* __restrict__ beta,
    const float* __restrict__ Wk, float* __restrict__ Fout,
    float* __restrict__ n2g, float* __restrict__ rnag, float* __restrict__ thrg)
{
    __shared__ float sh_h[4][128];
    __shared__ float sh_y[4][256];

    const int tid  = threadIdx.x;
    const int lane = tid & 63;
    const int r    = tid >> 6;
    const int v    = blockIdx.x * 4 + r;

    const float4* embed4 = (const float4*)embed;
    const float4* W1_4   = (const float4*)W1;
    const float4* W2_4   = (const float4*)W2;
    const float4* Wk_4   = (const float4*)Wk;

    if (lane < 32)
        *(float4*)&sh_h[r][lane * 4] = embed4[v * 32 + lane];
    __syncthreads();

    #pragma unroll
    for (int jj = 0; jj < 4; ++jj) {
        int j = jj * 64 + lane;
        const float4* wrow = W1_4 + j * 32;
        float acc = 0.f;
        #pragma unroll
        for (int c4 = 0; c4 < 32; ++c4)
            acc = fma4(*(const float4*)&sh_h[r][c4 * 4], wrow[c4], acc);
        sh_y[r][j] = fmaxf(acc + b1[j], 0.f);
    }
    __syncthreads();

    float xv[4];
    #pragma unroll
    for (int cc = 0; cc < 4; ++cc) {
        int c  = cc * 32 + (lane & 31);
        int hf = lane >> 5;
        const float4* wrow = W2_4 + c * 64 + hf * 32;
        float acc = 0.f;
        #pragma unroll
        for (int j4 = 0; j4 < 32; ++j4)
            acc = fma4(*(const float4*)&sh_y[r][(hf * 32 + j4) * 4], wrow[j4], acc);
        acc += __shfl_xor(acc, 32);
        xv[cc] = acc;
    }
    if (lane < 32) {
        #pragma unroll
        for (int cc = 0; cc < 4; ++cc) {
            int c = cc * 32 + lane;
            sh_h[r][c] = sh_h[r][c] + xv[cc] + b2[c];
        }
    }
    __syncthreads();

    {
        float2 x2 = *(const float2*)&sh_h[r][lane * 2];
        float s  = x2.x + x2.y;
        float s2 = x2.x * x2.x + x2.y * x2.y;
        s  += __shfl_xor(s, 1);  s  += __shfl_xor(s, 2);  s  += __shfl_xor(s, 4);
        s  += __shfl_xor(s, 8);  s  += __shfl_xor(s, 16); s  += __shfl_xor(s, 32);
        s2 += __shfl_xor(s2, 1); s2 += __shfl_xor(s2, 2); s2 += __shfl_xor(s2, 4);
        s2 += __shfl_xor(s2, 8); s2 += __shfl_xor(s2, 16); s2 += __shfl_xor(s2, 32);
        float mu   = s * (1.f / 128.f);
        float var  = s2 * (1.f / 128.f) - mu * mu;
        float rstd = 1.f / sqrtf(var + 1e-5f);
        float2 g2  = *(const float2*)&gamma[lane * 2];
        float2 be2 = *(const float2*)&beta[lane * 2];
        float2 o;
        o.x = (x2.x - mu) * rstd * g2.x + be2.x;
        o.y = (x2.y - mu) * rstd * g2.y + be2.y;
        *(float2*)&sh_h[r][lane * 2] = o;
    }
    __syncthreads();

    float fk0, fk1;
    {
        int k0 = lane, k1 = 64 + lane;
        const float4* w0 = Wk_4 + k0 * 32;
        const float4* w1 = Wk_4 + k1 * 32;
        float a0 = 0.f, a1 = 0.f;
        #pragma unroll
        for (int c4 = 0; c4 < 32; ++c4) {
            float4 h4 = *(const float4*)&sh_h[r][c4 * 4];
            a0 = fma4(h4, w0[c4], a0);
            a1 = fma4(h4, w1[c4], a1);
        }
        Fout[v * 128 + lane]      = a0;
        Fout[v * 128 + 64 + lane] = a1;
        fk0 = a0; fk1 = a1;
    }
    // per-vocab n2 / rna / thr
    {
        float n2 = fmaf(fk0, fk0, fk1 * fk1);
        n2 += __shfl_xor(n2, 1);  n2 += __shfl_xor(n2, 2);  n2 += __shfl_xor(n2, 4);
        n2 += __shfl_xor(n2, 8);  n2 += __shfl_xor(n2, 16); n2 += __shfl_xor(n2, 32);
        if (lane == 0) {
            n2g[v]  = n2;
            rnag[v] = 1.f / fmaxf(sqrtf(n2), 1e-12f);
            thrg[v] = 0.16f * n2;
        }
    }
}

// ---------------------------------------------------------------------------
// Kernel 2: gated delta-rule scan, wave=col-chunk layout + fused out-proj.
//   8 waves = 4 col-chunks (cc) x 2 row-halves (rh); lane owns row rh*64+l,
//   cols cc*32..+31 (m = 32 f32). k-chunks are wave-uniform: fetched from
//   L2-hot F via uniform global loads into a 3-slot register ring (VMEM, not
//   drained by the raw barrier). Per step: 4 partial b32 reads + 1 write +
//   2 red scalars + 4 table scalars of LDS only. Gate-decoupled matvec:
//     pre_{t+1} = praw(M_{t-1}·k_{t+1}) + g_t·rna_t·err_t[row]·d01[t]  (exact)
//   Epilogue: pre at t=254 IS the readout -> fused (read@Wr^T+br)@Wo^T+bo.
// ---------------------------------------------------------------------------
__global__ __launch_bounds__(512) void k_scan(
    const int* __restrict__ seq, const float* __restrict__ Fbuf,
    const float* __restrict__ n2g, const float* __restrict__ rnag,
    const float* __restrict__ thrg,
    const float* __restrict__ Wr, const float* __restrict__ br,
    const float* __restrict__ Wo, const float* __restrict__ bo,
    float* __restrict__ out)
{
    __shared__ float part_[2][4][128];   // parity, cc, row
    __shared__ float red_[2][2];         // parity, row-half
    __shared__ float rna_[256];
    __shared__ float thr_[256];
    __shared__ float d01_[256];
    __shared__ int   seqb_[256];

    const int tid  = threadIdx.x;
    const int lane = tid & 63;
    const int w    = tid >> 6;
    const int cc   = w & 3;
    const int rh   = w >> 2;
    const int row  = rh * 64 + lane;
    const int b    = blockIdx.x;
    const float4* F4 = (const float4*)Fbuf;

    // ---- prologue ----
    if (tid < 256) seqb_[tid] = seq[b * 256 + tid];
    __syncthreads();

    if (tid < 256) {
        int v = seqb_[tid];
        rna_[tid] = rnag[v];
        thr_[tid] = thrg[v];
    } else if (tid < 511) {
        int t = tid - 256;                       // 0..254
        int va = seqb_[t], vb = seqb_[t + 1];
        const float4* A  = F4 + va * 32;
        const float4* Bp = F4 + vb * 32;
        float a0 = 0.f, a1 = 0.f, a2 = 0.f, a3 = 0.f;
        #pragma unroll
        for (int u = 0; u < 8; ++u) {
            a0 = fma4(A[u],      Bp[u],      a0);
            a1 = fma4(A[8 + u],  Bp[8 + u],  a1);
            a2 = fma4(A[16 + u], Bp[16 + u], a2);
            a3 = fma4(A[24 + u], Bp[24 + u], a3);
        }
        d01_[t] = (a0 + a1) + (a2 + a3);
    }
    part_[0][tid >> 7][tid & 127] = 0.f;         // zero parity-0 partials
    if (tid == 0) red_[0][1] = 0.f;
    if (tid == 1) red_[0][0] = n2g[seqb_[0]];    // e2_0 = ||k_0||^2

    // per-lane / per-wave init (after seqb barrier)
    float errT = Fbuf[(size_t)seqb_[0] * 128 + row];   // err_0 = k_0[row]
    float ksA  = Fbuf[(size_t)seqb_[1] * 128 + row];   // kself_1
    float ksB  = 0.f;
    float4 m[8], kb0[8], kb1[8], kb2[8];
    {
        int v0 = seqb_[0], v1 = seqb_[1], v2 = seqb_[2];
        #pragma unroll
        for (int u = 0; u < 8; ++u) {
            m[u]   = make_float4(0.f, 0.f, 0.f, 0.f);
            kb0[u] = F4[(size_t)v0 * 32 + cc * 8 + u];
            kb1[u] = F4[(size_t)v1 * 32 + cc * 8 + u];
            kb2[u] = F4[(size_t)v2 * 32 + cc * 8 + u];
        }
    }
    __syncthreads();

#define REG(T, BU, BM, KSU, KSP)                                                \
  {                                                                             \
    const int t_ = (T), pr = t_ & 1, pw = pr ^ 1;                               \
    int sv2 = seqb_[t_ + 2];                                                    \
    int sv3 = seqb_[(t_ + 3 > 255) ? 255 : t_ + 3];                             \
    float p0 = part_[pr][0][row], p1 = part_[pr][1][row];                       \
    float p2 = part_[pr][2][row], p3 = part_[pr][3][row];                       \
    float r0 = red_[pr][0], r1 = red_[pr][1];                                   \
    float rnaT = rna_[t_], thrT = thr_[t_], d01T = d01_[t_];                    \
    float rnaN = rna_[t_ + 1];                                                  \
    float praw = (p0 + p1) + (p2 + p3);                                         \
    float E2 = r0 + r1;                                                         \
    float av = (E2 >= thrT) ? rnaT * errT : 0.f;                                \
    float pre = fmaf(av, d01T, praw);        /* = M_t · k_{t+1} exact */        \
    float errN = fmaf(-rnaN, pre, KSU);                                         \
    float e2p = wave_sum(errN * errN);                                          \
    if (cc == 0 && lane == 63) red_[pw][rh] = e2p;                              \
    KSP = Fbuf[(size_t)sv2 * 128 + row];     /* kself_{t+2} (VMEM) */           \
    _Pragma("unroll")                                                           \
    for (int u = 0; u < 8; ++u) {            /* update: m = M_t */              \
      m[u].x = fmaf(av, BU[u].x, m[u].x);                                       \
      m[u].y = fmaf(av, BU[u].y, m[u].y);                                       \
      m[u].z = fmaf(av, BU[u].z, m[u].z);                                       \
      m[u].w = fmaf(av, BU[u].w, m[u].w);                                       \
    }                                                                           \
    float q0 = 0.f, q1 = 0.f, q2 = 0.f, q3 = 0.f;                               \
    q0 = fma4(m[0], BM[0], q0); q1 = fma4(m[1], BM[1], q1);                     \
    q2 = fma4(m[2], BM[2], q2); q3 = fma4(m[3], BM[3], q3);                     \
    q0 = fma4(m[4], BM[4], q0); q1 = fma4(m[5], BM[5], q1);                     \
    q2 = fma4(m[6], BM[6], q2); q3 = fma4(m[7], BM[7], q3);                     \
    part_[pw][cc][row] = (q0 + q1) + (q2 + q3);  /* M_t·k_{t+2} partial */      \
    _Pragma("unroll")                                                           \
    for (int u = 0; u < 8; ++u)              /* refill BU <- k_{t+3} (VMEM) */  \
      BU[u] = F4[(size_t)sv3 * 32 + cc * 8 + u];                                \
    __builtin_amdgcn_sched_barrier(0);                                          \
    asm volatile("s_waitcnt lgkmcnt(0)" ::: "memory");                          \
    __builtin_amdgcn_sched_barrier(0);                                          \
    __builtin_amdgcn_s_barrier();                                               \
    __builtin_amdgcn_sched_barrier(0);                                          \
    errT = errN;                                                                \
  }

    for (int tt = 0; tt < 252; tt += 6) {
        REG(tt + 0, kb0, kb2, ksA, ksB);
        REG(tt + 1, kb1, kb0, ksB, ksA);
        REG(tt + 2, kb2, kb1, ksA, ksB);
        REG(tt + 3, kb0, kb2, ksB, ksA);
        REG(tt + 4, kb1, kb0, ksA, ksB);
        REG(tt + 5, kb2, kb1, ksB, ksA);
    }
    REG(252, kb0, kb2, ksA, ksB);
    REG(253, kb1, kb0, ksB, ksA);
#undef REG

    // ---- final step t=254: pre = M_254·k_255 = readout[row] ----
    float* rd_ = &part_[1][0][0];
    float* r2_ = &part_[1][1][0];
    {
        float p0 = part_[0][0][row], p1 = part_[0][1][row];
        float p2 = part_[0][2][row], p3 = part_[0][3][row];
        float praw = (p0 + p1) + (p2 + p3);          // M_253·k_255
        float E2 = red_[0][0] + red_[0][1];
        float av = (E2 >= thr_[254]) ? rna_[254] * errT : 0.f;
        float pre = fmaf(av, d01_[254], praw);       // M_254·k_255
        if (cc == 0) rd_[row] = pre;
    }
    __syncthreads();

    // ---- fused out-projection: out = (rd @ Wr^T + br) @ Wo^T + bo ----
    {
        int i = tid >> 2, q = tid & 3;
        const float4* Wr4 = (const float4*)Wr;
        const float4* rdv = (const float4*)rd_;
        float s = 0.f;
        #pragma unroll
        for (int u = 0; u < 8; ++u) s = fma4(rdv[q * 8 + u], Wr4[i * 32 + q * 8 + u], s);
        s += __shfl_xor(s, 1);
        s += __shfl_xor(s, 2);
        if (q == 0) r2_[i] = s + br[i];
    }
    __syncthreads();
    {
        int v = tid >> 1, h = tid & 1;
        const float4* Wo4 = (const float4*)Wo;
        const float4* r2v = (const float4*)r2_;
        float s = 0.f;
        #pragma unroll
        for (int u = 0; u < 16; ++u) s = fma4(r2v[h * 16 + u], Wo4[v * 32 + h * 16 + u], s);
        s += __shfl_xor(s, 1);
        if (h == 0) out[b * 256 + v] = s + bo[v];
    }
}

// ---------------------------------------------------------------------------
extern "C" void kernel_launch(void* const* d_in, const int* in_sizes, int n_in,
                              void* d_out, int out_size, void* d_ws, size_t ws_size,
                              hipStream_t stream) {
    const int*   seq   = (const int*)  d_in[0];
    const float* embed = (const float*)d_in[1];
    const float* W1    = (const float*)d_in[2];
    const float* b1    = (const float*)d_in[3];
    const float* W2    = (const float*)d_in[4];
    const float* b2    = (const float*)d_in[5];
    const float* gamma = (const float*)d_in[6];
    const float* beta  = (const float*)d_in[7];
    const float* Wk    = (const float*)d_in[8];
    const float* Wr    = (const float*)d_in[9];
    const float* br    = (const float*)d_in[10];
    const float* Wo    = (const float*)d_in[11];
    const float* bo    = (const float*)d_in[12];

    float* Fbuf = (float*)d_ws;                      // 256*128 f32 = 128 KiB
    float* n2g  = Fbuf + VS_ * H_;                   // 256
    float* rnag = n2g + VS_;                         // 256
    float* thrg = rnag + VS_;                        // 256
    float* out  = (float*)d_out;

    k_vffn<<<VS_ / 4, 256, 0, stream>>>(embed, W1, b1, W2, b2, gamma, beta, Wk,
                                        Fbuf, n2g, rnag, thrg);
    k_scan<<<B_, 512, 0, stream>>>(seq, Fbuf, n2g, rnag, thrg,
                                   Wr, br, Wo, bo, out);
}